// Round 8
// baseline (182.992 us; speedup 1.0000x reference)
//
#include <hip/hip_runtime.h>

// Problem constants (from reference setup_inputs)
#define BB    16
#define NN    8192
#define DD    128
#define MM    2048
#define TOPKK 512
#define TT    (BB*MM)     // 32768
#define BNN   (BB*NN)     // 131072
#define WINS  (BB*TOPKK)  // 8192

// ---------------- workspace layout (bytes) ----------------
#define WS_TAW     0           // float[WINS*DD]   4194304
#define WS_COUNTS  4194304     // int[TT]          131072
#define WS_AGG     4325376     // double[TT]       262144
#define WS_W       4587520     // double[B*384]    49152
#define WS_C       4636672     // double[B]        128
#define WS_IDX     4636800     // int[WINS]        32768
#define WS_OFFSETS 4669568     // int[TT+1]        131136 (padded)
#define WS_CURSOR  4800704     // int[TT]          131072
#define WS_LIST    4931776     // int[BNN]         524288
#define WS_ATT     5456064     // double[BNN]      1048576  (8-aligned)

// Per-batch precompute: query_b, alpha_b, w_b = Wa @ alpha_b, c_b. All f64.
__global__ __launch_bounds__(128) void k_prep(const float* __restrict__ q_head,
                                              const float* __restrict__ q_rel,
                                              const float* __restrict__ q_time,
                                              const float* __restrict__ Wq,
                                              const float* __restrict__ bq,
                                              const float* __restrict__ Wa,
                                              const float* __restrict__ ba,
                                              const float* __restrict__ Watt,
                                              const float* __restrict__ batt,
                                              double* __restrict__ w_out,   // B*384
                                              double* __restrict__ c_out) { // B
    int b = blockIdx.x;
    int d = threadIdx.x; // 0..127
    __shared__ double x_s[3*DD];
    __shared__ double alpha_s[DD];
    __shared__ double kpart[DD];
    x_s[d]        = (double)q_head[b*DD + d];
    x_s[DD + d]   = (double)q_rel [b*DD + d];
    x_s[2*DD + d] = (double)q_time[b*DD + d];
    __syncthreads();

    double acc = (double)bq[d];
    for (int k = 0; k < 3*DD; ++k) acc += x_s[k] * (double)Wq[k*DD + d];

    double W1 = (double)Watt[d];
    double W2 = (double)Watt[DD + d];
    double W3 = (double)Watt[2*DD + d];
    double a  = W1 * acc - W2 + W3;
    alpha_s[d] = a;
    kpart[d]   = acc * (W2 + W3) + (double)ba[d] * a;
    __syncthreads();

    for (int kk = d; kk < 3*DD; kk += DD) {
        double s = 0.0;
        for (int dd = 0; dd < DD; ++dd) s += (double)Wa[kk*DD + dd] * alpha_s[dd];
        w_out[b*3*DD + kk] = s;
    }
    if (d == 0) {
        double K = (double)batt[0];
        for (int dd = 0; dd < DD; ++dd) K += kpart[dd];
        c_out[b] = K;
    }
}

__global__ __launch_bounds__(256) void k_count(const int* __restrict__ tail_index,
                                               int* __restrict__ counts) {
    int i = blockIdx.x * 256 + threadIdx.x;
    if (i < BNN) atomicAdd(&counts[tail_index[i]], 1);
}

// Single-block exclusive scan of counts[T] -> offsets, cursor (int4-vectorized)
// Also zeros agg_att (removes a separate memset).
__global__ __launch_bounds__(1024) void k_scan(const int* __restrict__ counts,
                                               int* __restrict__ offsets,
                                               int* __restrict__ cursor,
                                               double* __restrict__ agg_att) {
    __shared__ int s[1024];
    int tid = threadIdx.x;
    int base = tid * 32;
    int c[32];
    #pragma unroll
    for (int j = 0; j < 8; ++j) {
        int4 v = *(const int4*)(counts + base + 4*j);
        c[4*j+0]=v.x; c[4*j+1]=v.y; c[4*j+2]=v.z; c[4*j+3]=v.w;
    }
    int sum = 0;
    #pragma unroll
    for (int j = 0; j < 32; ++j) sum += c[j];
    s[tid] = sum;
    __syncthreads();
    for (int off = 1; off < 1024; off <<= 1) {
        int v = (tid >= off) ? s[tid - off] : 0;
        __syncthreads();
        s[tid] += v;
        __syncthreads();
    }
    int run = s[tid] - sum;
    int o[32];
    #pragma unroll
    for (int j = 0; j < 32; ++j) { o[j] = run; run += c[j]; }
    #pragma unroll
    for (int j = 0; j < 8; ++j) {
        int4 v; v.x=o[4*j+0]; v.y=o[4*j+1]; v.z=o[4*j+2]; v.w=o[4*j+3];
        *(int4*)(offsets + base + 4*j) = v;
        *(int4*)(cursor  + base + 4*j) = v;
    }
    // zero agg_att[32768]
    double2 z2; z2.x = 0.0; z2.y = 0.0;
    #pragma unroll
    for (int j = 0; j < 16; ++j)
        *(double2*)(agg_att + base + 2*j) = z2;
    if (tid == 1023) offsets[TT] = run;
}

// ---------------- Phase A: streaming att + agg_att + CSR fill ----------------
// One row per 32-lane half-wave (float4/lane = 128 dims). One-shot wave
// (R6-measured best: at the ~3 TB/s read-stream wall). Leader lane also
// performs the CSR fill (cursor atomic + list write) — fuses k_fill.
__global__ __launch_bounds__(256) void k_att(const float* __restrict__ r_n,
                                             const float* __restrict__ t_n,
                                             const float* __restrict__ tm_n,
                                             const float* __restrict__ hidden,
                                             const float* __restrict__ Wrule,
                                             const float* __restrict__ brule,
                                             const int* __restrict__ tail_index,
                                             const double* __restrict__ w_all,
                                             const double* __restrict__ c_all,
                                             double* __restrict__ attArr,
                                             double* __restrict__ agg_att,
                                             int* __restrict__ cursor,
                                             int* __restrict__ list) {
    const int wave = threadIdx.x >> 6;
    const int lane = threadIdx.x & 63;
    const int half = lane >> 5;
    const int sl   = lane & 31;
    const int d0   = 4 * sl;
    const int row  = (blockIdx.x * 4 + wave) * 2 + half;
    const int b    = row >> 13;

    const double* w = w_all + b * 3 * DD;
    float w0[4], w1[4], w2[4];
    #pragma unroll
    for (int j = 0; j < 4; ++j) {
        w0[j] = (float)w[d0 + j];
        w1[j] = (float)w[DD + d0 + j];
        w2[j] = (float)w[2*DD + d0 + j];
    }
    const float4 wr = *(const float4*)(Wrule + d0);
    const double cb = c_all[b];
    const double br = (double)brule[0];

    long long base = (long long)row * DD + d0;
    float4 rv = *(const float4*)(r_n    + base);
    float4 tv = *(const float4*)(t_n    + base);
    float4 mv = *(const float4*)(tm_n   + base);
    float4 hv = *(const float4*)(hidden + base);

    double z1 = (double)rv.x*(double)w0[0] + (double)rv.y*(double)w0[1]
              + (double)rv.z*(double)w0[2] + (double)rv.w*(double)w0[3]
              + (double)tv.x*(double)w1[0] + (double)tv.y*(double)w1[1]
              + (double)tv.z*(double)w1[2] + (double)tv.w*(double)w1[3]
              + (double)mv.x*(double)w2[0] + (double)mv.y*(double)w2[1]
              + (double)mv.z*(double)w2[2] + (double)mv.w*(double)w2[3];
    double z2 = (double)hv.x*(double)wr.x + (double)hv.y*(double)wr.y
              + (double)hv.z*(double)wr.z + (double)hv.w*(double)wr.w;
    #pragma unroll
    for (int o = 16; o > 0; o >>= 1) {
        z1 += __shfl_xor(z1, o);
        z2 += __shfl_xor(z2, o);
    }
    // parity exp dedup: even lanes exp(-(z1+cb)), odd lanes exp(-(z2+br))
    double x  = (lane & 1) ? (z2 + br) : (z1 + cb);
    double ex = exp(-x);
    double exo = __shfl_xor(ex, 1);
    double att_d = 0.5 * (2.0 + ex + exo) / ((1.0 + ex) * (1.0 + exo));

    if (sl == 0) {
        attArr[row] = att_d;
        int t = tail_index[row];
        unsafeAtomicAdd(&agg_att[t], att_d);
        int p = atomicAdd(&cursor[t], 1);   // fused CSR fill
        list[p] = row;
    }
}

// Per-batch exact top-k: bitonic sort of M=2048 (value desc, index asc).
__global__ __launch_bounds__(1024) void k_topk(const double* __restrict__ agg_att,
                                               const int* __restrict__ tail_nodes,
                                               int* __restrict__ idx_out,
                                               float* __restrict__ out_nodes) {
    int b = blockIdx.x;
    __shared__ double v[MM];
    __shared__ int    id[MM];
    for (int i = threadIdx.x; i < MM; i += blockDim.x) {
        v[i]  = agg_att[b*MM + i];
        id[i] = i;
    }
    __syncthreads();
    for (int k = 2; k <= MM; k <<= 1) {
        for (int j = k >> 1; j > 0; j >>= 1) {
            for (int i = threadIdx.x; i < MM; i += blockDim.x) {
                int ixj = i ^ j;
                if (ixj > i) {
                    double va = v[i], vb = v[ixj];
                    int    ia = id[i], ib = id[ixj];
                    bool aBeforeB = (va > vb) || (va == vb && ia < ib);
                    bool wantBefore = ((i & k) == 0);
                    if (wantBefore != aBeforeB) {
                        v[i] = vb; v[ixj] = va;
                        id[i] = ib; id[ixj] = ia;
                    }
                }
            }
            __syncthreads();
        }
    }
    for (int r = threadIdx.x; r < TOPKK; r += blockDim.x) {
        int t = b * MM + id[r];
        idx_out[b*TOPKK + r] = t;
        out_nodes[(b*TOPKK + r)*2 + 0] = (float)tail_nodes[t*3 + 1];
        out_nodes[(b*TOPKK + r)*2 + 1] = (float)tail_nodes[t*3 + 2];
    }
}

// ---------------- Phase C: aggregate ONLY winning segments ----------------
__global__ __launch_bounds__(256) void k_aggW(const float* __restrict__ r_n,
                                              const float* __restrict__ tm_n,
                                              const float* __restrict__ hidden,
                                              const float* __restrict__ q_head,
                                              const float* __restrict__ tail_emd,
                                              const int* __restrict__ offsets,
                                              const int* __restrict__ list,
                                              const double* __restrict__ attArr,
                                              const int* __restrict__ idx_ws,
                                              float* __restrict__ taw,
                                              float* __restrict__ out_hid) {
    const int hw = threadIdx.x >> 5;
    const int sl = threadIdx.x & 31;
    const int d0 = 4 * sl;
    const int wi = blockIdx.x * 8 + hw;      // winner index, rank order
    const int t  = idx_ws[wi];
    const int b  = t >> 11;                  // t / M

    const float4 qh = *(const float4*)(q_head + b*DD + d0);
    const int start = offsets[t];
    const int end   = offsets[t + 1];

    float p0 = 0.f, p1 = 0.f, p2 = 0.f, p3 = 0.f;
    float h0 = 0.f, h1 = 0.f, h2 = 0.f, h3 = 0.f;
    double asum = 0.0;

    for (int e = start; e < end; ++e) {
        int row = list[e];
        long long base = (long long)row * DD + d0;
        float4 rv = *(const float4*)(r_n    + base);
        float4 mv = *(const float4*)(tm_n   + base);
        float4 hv = *(const float4*)(hidden + base);
        double attd = attArr[row];
        float  att  = (float)attd;
        p0 += att * (rv.x + mv.x); p1 += att * (rv.y + mv.y);
        p2 += att * (rv.z + mv.z); p3 += att * (rv.w + mv.w);
        h0 += hv.x; h1 += hv.y; h2 += hv.z; h3 += hv.w;
        asum += attd;
    }

    float A = (float)asum;
    long long ot = (long long)t  * DD + d0;
    long long ow = (long long)wi * DD + d0;
    float4 te = *(const float4*)(tail_emd + ot);
    float4 ta;
    ta.x = te.x + A*qh.x + p0; ta.y = te.y + A*qh.y + p1;
    ta.z = te.z + A*qh.z + p2; ta.w = te.w + A*qh.w + p3;
    *(float4*)(taw + ow) = ta;
    float4 nh; nh.x = h0; nh.y = h1; nh.z = h2; nh.w = h3;
    *(float4*)(out_hid + ow) = nh;
}

// Epilogue: emd = taw @ Wout + bout (compact, contiguous rows).
// 16 rows/block halves Wout L2 traffic vs 8.
#define ROWS_PER_BLK 16
__global__ __launch_bounds__(128) void k_out(const float* __restrict__ taw,
                                             const float* __restrict__ Wout,
                                             const float* __restrict__ bout,
                                             float* __restrict__ out_emd) {
    int c = threadIdx.x;
    int pair0 = blockIdx.x * ROWS_PER_BLK;
    __shared__ float a_s[ROWS_PER_BLK][DD];
    #pragma unroll
    for (int j = 0; j < ROWS_PER_BLK; ++j)
        a_s[j][c] = taw[(long long)(pair0 + j) * DD + c];
    __syncthreads();
    float acc[ROWS_PER_BLK];
    float bc = bout[c];
    #pragma unroll
    for (int j = 0; j < ROWS_PER_BLK; ++j) acc[j] = bc;
    for (int d = 0; d < DD; ++d) {
        float wv = Wout[d*DD + c];
        #pragma unroll
        for (int j = 0; j < ROWS_PER_BLK; ++j)
            acc[j] = fmaf(a_s[j][d], wv, acc[j]);
    }
    #pragma unroll
    for (int j = 0; j < ROWS_PER_BLK; ++j)
        out_emd[(long long)(pair0 + j) * DD + c] = acc[j];
}

extern "C" void kernel_launch(void* const* d_in, const int* in_sizes, int n_in,
                              void* d_out, int out_size, void* d_ws, size_t ws_size,
                              hipStream_t stream) {
    const float* q_head   = (const float*)d_in[0];
    const float* q_rel    = (const float*)d_in[1];
    const float* q_time   = (const float*)d_in[2];
    const float* r_n      = (const float*)d_in[3];
    const float* t_n      = (const float*)d_in[4];
    const float* tm_n     = (const float*)d_in[5];
    const float* hidden   = (const float*)d_in[6];
    const float* tail_emd = (const float*)d_in[7];
    const int*   tail_index = (const int*)d_in[8];
    const int*   tail_nodes = (const int*)d_in[9];
    const float* Wq   = (const float*)d_in[10];
    const float* bq   = (const float*)d_in[11];
    const float* Wa   = (const float*)d_in[12];
    const float* ba   = (const float*)d_in[13];
    const float* Watt = (const float*)d_in[14];
    const float* batt = (const float*)d_in[15];
    const float* Wrule = (const float*)d_in[16];
    const float* brule = (const float*)d_in[17];
    const float* Wout = (const float*)d_in[18];
    const float* bout = (const float*)d_in[19];

    char* ws = (char*)d_ws;
    float*  taw     = (float*) (ws + WS_TAW);
    int*    counts  = (int*)   (ws + WS_COUNTS);
    double* agg_att = (double*)(ws + WS_AGG);
    double* w_all   = (double*)(ws + WS_W);
    double* c_all   = (double*)(ws + WS_C);
    int*    idx_ws  = (int*)   (ws + WS_IDX);
    int*    offsets = (int*)   (ws + WS_OFFSETS);
    int*    cursor  = (int*)   (ws + WS_CURSOR);
    int*    list    = (int*)   (ws + WS_LIST);
    double* attArr  = (double*)(ws + WS_ATT);

    float* out       = (float*)d_out;
    float* out_nodes = out;                      // B*TOPK*2
    float* out_emd   = out + BB*TOPKK*2;         // B*TOPK*D
    float* out_hid   = out_emd + BB*TOPKK*DD;    // B*TOPK*D

    hipMemsetAsync(counts, 0, TT * sizeof(int), stream);
    hipLaunchKernelGGL(k_prep, dim3(BB), dim3(DD), 0, stream,
                       q_head, q_rel, q_time, Wq, bq, Wa, ba, Watt, batt,
                       w_all, c_all);
    hipLaunchKernelGGL(k_count, dim3(BNN/256), dim3(256), 0, stream,
                       tail_index, counts);
    hipLaunchKernelGGL(k_scan, dim3(1), dim3(1024), 0, stream,
                       counts, offsets, cursor, agg_att);
    hipLaunchKernelGGL(k_att, dim3(BNN/8), dim3(256), 0, stream,
                       r_n, t_n, tm_n, hidden, Wrule, brule,
                       tail_index, w_all, c_all, attArr, agg_att,
                       cursor, list);
    hipLaunchKernelGGL(k_topk, dim3(BB), dim3(1024), 0, stream,
                       agg_att, tail_nodes, idx_ws, out_nodes);
    hipLaunchKernelGGL(k_aggW, dim3(WINS/8), dim3(256), 0, stream,
                       r_n, tm_n, hidden, q_head, tail_emd,
                       offsets, list, attArr, idx_ws, taw, out_hid);
    hipLaunchKernelGGL(k_out, dim3(WINS/ROWS_PER_BLK), dim3(DD), 0, stream,
                       taw, Wout, bout, out_emd);
}

// Round 9
// 178.254 us; speedup vs baseline: 1.0266x; 1.0266x over previous
//
#include <hip/hip_runtime.h>

// Problem constants (from reference setup_inputs)
#define BB    16
#define NN    8192
#define DD    128
#define MM    2048
#define TOPKK 512
#define TT    (BB*MM)     // 32768
#define BNN   (BB*NN)     // 131072
#define WINS  (BB*TOPKK)  // 8192

// ---------------- workspace layout (bytes) ----------------
#define WS_COUNTS  0           // int[TT]          131072
#define WS_AGG     131072      // double[TT]       262144
#define WS_W32     393216      // float[B*384]     24576
#define WS_C       417792      // double[B]        128
#define WS_IDX     417920      // int[WINS]        32768
#define WS_OFFSETS 450688      // int[TT+1]        131104 (padded)
#define WS_CURSOR  581792      // int[TT]          131072
#define WS_LIST    712864      // int[BNN]         524288
#define WS_ATT     1237152     // double[BNN]      1048576 (8-aligned)

#define GLD_LDS16(gp, lp) \
    __builtin_amdgcn_global_load_lds( \
        (const __attribute__((address_space(1))) void*)(gp), \
        (__attribute__((address_space(3))) void*)(lp), 16, 0, 0)

// Per-batch precompute: query_b, alpha_b, w_b = Wa @ alpha_b (f32 out), c_b.
__global__ __launch_bounds__(128) void k_prep(const float* __restrict__ q_head,
                                              const float* __restrict__ q_rel,
                                              const float* __restrict__ q_time,
                                              const float* __restrict__ Wq,
                                              const float* __restrict__ bq,
                                              const float* __restrict__ Wa,
                                              const float* __restrict__ ba,
                                              const float* __restrict__ Watt,
                                              const float* __restrict__ batt,
                                              float* __restrict__ w32_out,  // B*384 f32
                                              double* __restrict__ c_out) { // B
    int b = blockIdx.x;
    int d = threadIdx.x; // 0..127
    __shared__ double x_s[3*DD];
    __shared__ double alpha_s[DD];
    __shared__ double kpart[DD];
    x_s[d]        = (double)q_head[b*DD + d];
    x_s[DD + d]   = (double)q_rel [b*DD + d];
    x_s[2*DD + d] = (double)q_time[b*DD + d];
    __syncthreads();

    double acc = (double)bq[d];
    for (int k = 0; k < 3*DD; ++k) acc += x_s[k] * (double)Wq[k*DD + d];

    double W1 = (double)Watt[d];
    double W2 = (double)Watt[DD + d];
    double W3 = (double)Watt[2*DD + d];
    double a  = W1 * acc - W2 + W3;
    alpha_s[d] = a;
    kpart[d]   = acc * (W2 + W3) + (double)ba[d] * a;
    __syncthreads();

    for (int kk = d; kk < 3*DD; kk += DD) {
        double s = 0.0;
        for (int dd = 0; dd < DD; ++dd) s += (double)Wa[kk*DD + dd] * alpha_s[dd];
        w32_out[b*3*DD + kk] = (float)s;   // per-batch f32 rounding (validated R4+)
    }
    if (d == 0) {
        double K = (double)batt[0];
        for (int dd = 0; dd < DD; ++dd) K += kpart[dd];
        c_out[b] = K;
    }
}

__global__ __launch_bounds__(256) void k_count(const int* __restrict__ tail_index,
                                               int* __restrict__ counts) {
    int i = blockIdx.x * 256 + threadIdx.x;
    if (i < BNN) atomicAdd(&counts[tail_index[i]], 1);
}

// Single-block exclusive scan of counts[T] -> offsets, cursor (int4-vectorized)
// Also zeros agg_att.
__global__ __launch_bounds__(1024) void k_scan(const int* __restrict__ counts,
                                               int* __restrict__ offsets,
                                               int* __restrict__ cursor,
                                               double* __restrict__ agg_att) {
    __shared__ int s[1024];
    int tid = threadIdx.x;
    int base = tid * 32;
    int c[32];
    #pragma unroll
    for (int j = 0; j < 8; ++j) {
        int4 v = *(const int4*)(counts + base + 4*j);
        c[4*j+0]=v.x; c[4*j+1]=v.y; c[4*j+2]=v.z; c[4*j+3]=v.w;
    }
    int sum = 0;
    #pragma unroll
    for (int j = 0; j < 32; ++j) sum += c[j];
    s[tid] = sum;
    __syncthreads();
    for (int off = 1; off < 1024; off <<= 1) {
        int v = (tid >= off) ? s[tid - off] : 0;
        __syncthreads();
        s[tid] += v;
        __syncthreads();
    }
    int run = s[tid] - sum;
    int o[32];
    #pragma unroll
    for (int j = 0; j < 32; ++j) { o[j] = run; run += c[j]; }
    #pragma unroll
    for (int j = 0; j < 8; ++j) {
        int4 v; v.x=o[4*j+0]; v.y=o[4*j+1]; v.z=o[4*j+2]; v.w=o[4*j+3];
        *(int4*)(offsets + base + 4*j) = v;
        *(int4*)(cursor  + base + 4*j) = v;
    }
    double2 z2; z2.x = 0.0; z2.y = 0.0;
    #pragma unroll
    for (int j = 0; j < 16; ++j)
        *(double2*)(agg_att + base + 2*j) = z2;
    if (tid == 1023) offsets[TT] = run;
}

__device__ __forceinline__ double dot4d(const float4 a, const float4 w) {
    return (double)a.x*(double)w.x + (double)a.y*(double)w.y
         + (double)a.z*(double)w.z + (double)a.w*(double)w.w;
}

// ---------------- Phase A: LDS-staged att + agg_att + CSR fill ----------------
// Per block: 16 rows staged into 32KB LDS via async global_load_lds (wave wv
// stages array wv; 8 x 1KB instrs, no VGPR dest, no chain). __syncthreads
// drains vmcnt. Then 8 half-waves compute 2 rows each from LDS.
#define TROWS 16
__global__ __launch_bounds__(256) void k_att(const float* __restrict__ r_n,
                                             const float* __restrict__ t_n,
                                             const float* __restrict__ tm_n,
                                             const float* __restrict__ hidden,
                                             const float* __restrict__ w32_all,
                                             const double* __restrict__ c_all,
                                             const float* __restrict__ Wrule,
                                             const float* __restrict__ brule,
                                             const int* __restrict__ tail_index,
                                             double* __restrict__ attArr,
                                             double* __restrict__ agg_att,
                                             int* __restrict__ cursor,
                                             int* __restrict__ list) {
    __shared__ float buf[4][TROWS*DD];   // 4 x 8KB = 32KB
    const int tid  = threadIdx.x;
    const int wv   = tid >> 6;
    const int lane = tid & 63;
    const int rowBase = blockIdx.x * TROWS;
    const int b = rowBase >> 13;

    // async stage: wave wv stages array wv (16 rows x 512B = 8 x 1KB)
    {
        const float* src = (wv == 0) ? r_n : (wv == 1) ? t_n : (wv == 2) ? tm_n : hidden;
        const float* sp = src + (long long)rowBase * DD;
        float* dst = &buf[wv][0];
        #pragma unroll
        for (int j = 0; j < 8; ++j)
            GLD_LDS16(sp + j*256 + lane*4, dst + j*256);
    }

    // per-lane weights + tail_index prefetch while staging flies
    const int sl = lane & 31;
    const int d0 = 4 * sl;
    const int hw = tid >> 5;                 // half-wave 0..7
    const float* w = w32_all + b * 3 * DD;
    const float4 w0 = *(const float4*)(w + d0);
    const float4 w1 = *(const float4*)(w + DD + d0);
    const float4 w2 = *(const float4*)(w + 2*DD + d0);
    const float4 wr = *(const float4*)(Wrule + d0);
    const double cb = c_all[b];
    const double br = (double)brule[0];
    int tpre[2];
    tpre[0] = tail_index[rowBase + hw*2 + 0];
    tpre[1] = tail_index[rowBase + hw*2 + 1];

    __syncthreads();   // drains vmcnt(0) before barrier (compiler-emitted)

    #pragma unroll
    for (int rr = 0; rr < 2; ++rr) {
        const int rl  = hw * 2 + rr;
        const int row = rowBase + rl;
        float4 rv = *(const float4*)(&buf[0][rl*DD + d0]);
        float4 tv = *(const float4*)(&buf[1][rl*DD + d0]);
        float4 mv = *(const float4*)(&buf[2][rl*DD + d0]);
        float4 hv = *(const float4*)(&buf[3][rl*DD + d0]);

        double z1 = dot4d(rv, w0) + dot4d(tv, w1) + dot4d(mv, w2);
        double z2 = dot4d(hv, wr);
        #pragma unroll
        for (int o = 16; o > 0; o >>= 1) {
            z1 += __shfl_xor(z1, o);
            z2 += __shfl_xor(z2, o);
        }
        // parity exp dedup: even lanes exp(-(z1+cb)), odd lanes exp(-(z2+br))
        double x   = (lane & 1) ? (z2 + br) : (z1 + cb);
        double ex  = exp(-x);
        double exo = __shfl_xor(ex, 1);
        double att = 0.5 * (2.0 + ex + exo) / ((1.0 + ex) * (1.0 + exo));

        if (sl == 0) {
            attArr[row] = att;
            int t = tpre[rr];
            unsafeAtomicAdd(&agg_att[t], att);
            int p = atomicAdd(&cursor[t], 1);   // fused CSR fill
            list[p] = row;
        }
    }
}

// Per-batch exact top-k: bitonic sort of M=2048 (value desc, index asc).
__global__ __launch_bounds__(1024) void k_topk(const double* __restrict__ agg_att,
                                               const int* __restrict__ tail_nodes,
                                               int* __restrict__ idx_out,
                                               float* __restrict__ out_nodes) {
    int b = blockIdx.x;
    __shared__ double v[MM];
    __shared__ int    id[MM];
    for (int i = threadIdx.x; i < MM; i += blockDim.x) {
        v[i]  = agg_att[b*MM + i];
        id[i] = i;
    }
    __syncthreads();
    for (int k = 2; k <= MM; k <<= 1) {
        for (int j = k >> 1; j > 0; j >>= 1) {
            for (int i = threadIdx.x; i < MM; i += blockDim.x) {
                int ixj = i ^ j;
                if (ixj > i) {
                    double va = v[i], vb = v[ixj];
                    int    ia = id[i], ib = id[ixj];
                    bool aBeforeB = (va > vb) || (va == vb && ia < ib);
                    bool wantBefore = ((i & k) == 0);
                    if (wantBefore != aBeforeB) {
                        v[i] = vb; v[ixj] = va;
                        id[i] = ib; id[ixj] = ia;
                    }
                }
            }
            __syncthreads();
        }
    }
    for (int r = threadIdx.x; r < TOPKK; r += blockDim.x) {
        int t = b * MM + id[r];
        idx_out[b*TOPKK + r] = t;
        out_nodes[(b*TOPKK + r)*2 + 0] = (float)tail_nodes[t*3 + 1];
        out_nodes[(b*TOPKK + r)*2 + 1] = (float)tail_nodes[t*3 + 2];
    }
}

// ---------------- Fused Phase C + epilogue ----------------
// Block handles 16 winners: gather-accumulate into LDS (half-wave x 2 winners),
// then GEMM a_s[16][128] @ Wout directly to out_emd. No taw round-trip.
__global__ __launch_bounds__(256) void k_aggWO(const float* __restrict__ r_n,
                                               const float* __restrict__ tm_n,
                                               const float* __restrict__ hidden,
                                               const float* __restrict__ q_head,
                                               const float* __restrict__ tail_emd,
                                               const int* __restrict__ offsets,
                                               const int* __restrict__ list,
                                               const double* __restrict__ attArr,
                                               const int* __restrict__ idx_ws,
                                               const float* __restrict__ Wout,
                                               const float* __restrict__ bout,
                                               float* __restrict__ out_emd,
                                               float* __restrict__ out_hid) {
    __shared__ float a_s[16][DD];   // 8KB
    const int tid = threadIdx.x;
    const int hw  = tid >> 5;
    const int sl  = tid & 31;
    const int d0  = 4 * sl;
    const int w0i = blockIdx.x * 16;

    #pragma unroll
    for (int rr = 0; rr < 2; ++rr) {
        const int wi = w0i + hw * 2 + rr;
        const int t  = idx_ws[wi];
        const int b  = t >> 11;
        const float4 qh = *(const float4*)(q_head + b*DD + d0);
        const int start = offsets[t];
        const int end   = offsets[t + 1];

        float p0 = 0.f, p1 = 0.f, p2 = 0.f, p3 = 0.f;
        float h0 = 0.f, h1 = 0.f, h2 = 0.f, h3 = 0.f;
        double asum = 0.0;
        for (int e = start; e < end; ++e) {
            int row = list[e];
            long long base = (long long)row * DD + d0;
            float4 rv = *(const float4*)(r_n    + base);
            float4 mv = *(const float4*)(tm_n   + base);
            float4 hv = *(const float4*)(hidden + base);
            double attd = attArr[row];
            float  att  = (float)attd;
            p0 += att * (rv.x + mv.x); p1 += att * (rv.y + mv.y);
            p2 += att * (rv.z + mv.z); p3 += att * (rv.w + mv.w);
            h0 += hv.x; h1 += hv.y; h2 += hv.z; h3 += hv.w;
            asum += attd;
        }
        float A = (float)asum;
        long long ot = (long long)t * DD + d0;
        float4 te = *(const float4*)(tail_emd + ot);
        float4 ta;
        ta.x = te.x + A*qh.x + p0; ta.y = te.y + A*qh.y + p1;
        ta.z = te.z + A*qh.z + p2; ta.w = te.w + A*qh.w + p3;
        *(float4*)(&a_s[hw*2 + rr][d0]) = ta;
        float4 nh; nh.x = h0; nh.y = h1; nh.z = h2; nh.w = h3;
        *(float4*)(out_hid + (long long)wi * DD + d0) = nh;
    }
    __syncthreads();

    // GEMM phase: 256 threads = 2 row-halves x 128 columns
    const int c  = tid & 127;
    const int j0 = (tid >> 7) * 8;
    float acc[8];
    const float bc = bout[c];
    #pragma unroll
    for (int j = 0; j < 8; ++j) acc[j] = bc;
    for (int d = 0; d < DD; ++d) {
        float wvv = Wout[d*DD + c];
        #pragma unroll
        for (int j = 0; j < 8; ++j)
            acc[j] = fmaf(a_s[j0 + j][d], wvv, acc[j]);
    }
    #pragma unroll
    for (int j = 0; j < 8; ++j)
        out_emd[(long long)(w0i + j0 + j) * DD + c] = acc[j];
}

extern "C" void kernel_launch(void* const* d_in, const int* in_sizes, int n_in,
                              void* d_out, int out_size, void* d_ws, size_t ws_size,
                              hipStream_t stream) {
    const float* q_head   = (const float*)d_in[0];
    const float* q_rel    = (const float*)d_in[1];
    const float* q_time   = (const float*)d_in[2];
    const float* r_n      = (const float*)d_in[3];
    const float* t_n      = (const float*)d_in[4];
    const float* tm_n     = (const float*)d_in[5];
    const float* hidden   = (const float*)d_in[6];
    const float* tail_emd = (const float*)d_in[7];
    const int*   tail_index = (const int*)d_in[8];
    const int*   tail_nodes = (const int*)d_in[9];
    const float* Wq   = (const float*)d_in[10];
    const float* bq   = (const float*)d_in[11];
    const float* Wa   = (const float*)d_in[12];
    const float* ba   = (const float*)d_in[13];
    const float* Watt = (const float*)d_in[14];
    const float* batt = (const float*)d_in[15];
    const float* Wrule = (const float*)d_in[16];
    const float* brule = (const float*)d_in[17];
    const float* Wout = (const float*)d_in[18];
    const float* bout = (const float*)d_in[19];

    char* ws = (char*)d_ws;
    int*    counts  = (int*)   (ws + WS_COUNTS);
    double* agg_att = (double*)(ws + WS_AGG);
    float*  w32     = (float*) (ws + WS_W32);
    double* c_all   = (double*)(ws + WS_C);
    int*    idx_ws  = (int*)   (ws + WS_IDX);
    int*    offsets = (int*)   (ws + WS_OFFSETS);
    int*    cursor  = (int*)   (ws + WS_CURSOR);
    int*    list    = (int*)   (ws + WS_LIST);
    double* attArr  = (double*)(ws + WS_ATT);

    float* out       = (float*)d_out;
    float* out_nodes = out;                      // B*TOPK*2
    float* out_emd   = out + BB*TOPKK*2;         // B*TOPK*D
    float* out_hid   = out_emd + BB*TOPKK*DD;    // B*TOPK*D

    hipMemsetAsync(counts, 0, TT * sizeof(int), stream);
    hipLaunchKernelGGL(k_prep, dim3(BB), dim3(DD), 0, stream,
                       q_head, q_rel, q_time, Wq, bq, Wa, ba, Watt, batt,
                       w32, c_all);
    hipLaunchKernelGGL(k_count, dim3(BNN/256), dim3(256), 0, stream,
                       tail_index, counts);
    hipLaunchKernelGGL(k_scan, dim3(1), dim3(1024), 0, stream,
                       counts, offsets, cursor, agg_att);
    hipLaunchKernelGGL(k_att, dim3(BNN/TROWS), dim3(256), 0, stream,
                       r_n, t_n, tm_n, hidden, w32, c_all, Wrule, brule,
                       tail_index, attArr, agg_att, cursor, list);
    hipLaunchKernelGGL(k_topk, dim3(BB), dim3(1024), 0, stream,
                       agg_att, tail_nodes, idx_ws, out_nodes);
    hipLaunchKernelGGL(k_aggWO, dim3(WINS/16), dim3(256), 0, stream,
                       r_n, tm_n, hidden, q_head, tail_emd,
                       offsets, list, attArr, idx_ws, Wout, bout,
                       out_emd, out_hid);
}

// Round 10
// 174.289 us; speedup vs baseline: 1.0499x; 1.0227x over previous
//
#include <hip/hip_runtime.h>

// Problem constants (from reference setup_inputs)
#define BB    16
#define NN    8192
#define DD    128
#define MM    2048
#define TOPKK 512
#define TT    (BB*MM)     // 32768
#define BNN   (BB*NN)     // 131072
#define WINS  (BB*TOPKK)  // 8192
#define CAP   24          // max rows/segment slotted (Poisson(4): P(>=24) ~ 1e-12)
#define OVCAP 4096

// ---------------- workspace layout (bytes) ----------------
#define WS_COUNTS  0           // int[TT]        131072   } one memset
#define WS_AGG     131072      // double[TT]     262144   }
#define WS_OVC     393216      // int[16]        64       }
#define WS_W32     393280      // float[B*384]   24576
#define WS_C       417856      // double[B]      128
#define WS_IDX     417984      // int[WINS]      32768
#define WS_ATT     450752      // double[BNN]    1048576
#define WS_LIST2   1499328     // int[TT*CAP]    3145728
#define WS_OVBUF   4645056     // int2[OVCAP]    32768

#define GLD_LDS16(gp, lp) \
    __builtin_amdgcn_global_load_lds( \
        (const __attribute__((address_space(1))) void*)(gp), \
        (__attribute__((address_space(3))) void*)(lp), 16, 0, 0)

// Per-batch precompute: query_b, alpha_b, w_b = Wa @ alpha_b (f32 out), c_b.
__global__ __launch_bounds__(128) void k_prep(const float* __restrict__ q_head,
                                              const float* __restrict__ q_rel,
                                              const float* __restrict__ q_time,
                                              const float* __restrict__ Wq,
                                              const float* __restrict__ bq,
                                              const float* __restrict__ Wa,
                                              const float* __restrict__ ba,
                                              const float* __restrict__ Watt,
                                              const float* __restrict__ batt,
                                              float* __restrict__ w32_out,  // B*384 f32
                                              double* __restrict__ c_out) { // B
    int b = blockIdx.x;
    int d = threadIdx.x; // 0..127
    __shared__ double x_s[3*DD];
    __shared__ double alpha_s[DD];
    __shared__ double kpart[DD];
    x_s[d]        = (double)q_head[b*DD + d];
    x_s[DD + d]   = (double)q_rel [b*DD + d];
    x_s[2*DD + d] = (double)q_time[b*DD + d];
    __syncthreads();

    double acc = (double)bq[d];
    for (int k = 0; k < 3*DD; ++k) acc += x_s[k] * (double)Wq[k*DD + d];

    double W1 = (double)Watt[d];
    double W2 = (double)Watt[DD + d];
    double W3 = (double)Watt[2*DD + d];
    double a  = W1 * acc - W2 + W3;
    alpha_s[d] = a;
    kpart[d]   = acc * (W2 + W3) + (double)ba[d] * a;
    __syncthreads();

    for (int kk = d; kk < 3*DD; kk += DD) {
        double s = 0.0;
        for (int dd = 0; dd < DD; ++dd) s += (double)Wa[kk*DD + dd] * alpha_s[dd];
        w32_out[b*3*DD + kk] = (float)s;   // per-batch f32 rounding (validated R4+)
    }
    if (d == 0) {
        double K = (double)batt[0];
        for (int dd = 0; dd < DD; ++dd) K += kpart[dd];
        c_out[b] = K;
    }
}

__device__ __forceinline__ double dot4d(const float4 a, const float4 w) {
    return (double)a.x*(double)w.x + (double)a.y*(double)w.y
         + (double)a.z*(double)w.z + (double)a.w*(double)w.w;
}

// ---------------- Phase A: persistent double-buffered streaming ----------------
// 2048 blocks x 8 tiles x 8 rows. Per tile: each wave stages its array's 4KB
// via 4 global_load_lds (wave-uniform LDS dst), counted vmcnt(4) keeps next
// tile's loads in flight across raw s_barriers (never drain to 0 mid-loop).
// Fused: attArr write + f64 agg_att atomic + capped-slot CSR fill.
#define TROWS 8
#define TILES 8
#define ATT_BLOCKS (BNN/(TROWS*TILES))   // 2048
__global__ __launch_bounds__(256) void k_att(const float* __restrict__ r_n,
                                             const float* __restrict__ t_n,
                                             const float* __restrict__ tm_n,
                                             const float* __restrict__ hidden,
                                             const float* __restrict__ w32_all,
                                             const double* __restrict__ c_all,
                                             const float* __restrict__ Wrule,
                                             const float* __restrict__ brule,
                                             const int* __restrict__ tail_index,
                                             double* __restrict__ attArr,
                                             double* __restrict__ agg_att,
                                             int* __restrict__ counts,
                                             int* __restrict__ list2,
                                             int* __restrict__ ovCnt,
                                             int2* __restrict__ ovBuf) {
    __shared__ float buf[2][4][TROWS*DD];   // 32 KB
    const int tid  = threadIdx.x;
    const int wv   = tid >> 6;
    const int lane = tid & 63;
    const int hw   = tid >> 5;              // half-wave 0..7 = row-in-tile
    const int sl   = tid & 31;
    const int d0   = 4 * sl;
    const int rowBlk = blockIdx.x * (TROWS * TILES);  // 64 rows, single batch
    const int b = rowBlk >> 13;

    const float* src = (wv == 0) ? r_n : (wv == 1) ? t_n : (wv == 2) ? tm_n : hidden;

    const float* w = w32_all + b * 3 * DD;
    const float4 w0 = *(const float4*)(w + d0);
    const float4 w1 = *(const float4*)(w + DD + d0);
    const float4 w2 = *(const float4*)(w + 2*DD + d0);
    const float4 wr = *(const float4*)(Wrule + d0);
    const double cb = c_all[b];
    const double br = (double)brule[0];

    int tpre[TILES];
    #pragma unroll
    for (int i = 0; i < TILES; ++i)
        tpre[i] = tail_index[rowBlk + i*TROWS + hw];

    // prologue: stage tile 0 into buf[0]
    {
        const float* sp = src + (long long)rowBlk * DD;
        float* dst = &buf[0][wv][0];
        #pragma unroll
        for (int j = 0; j < 4; ++j)
            GLD_LDS16(sp + j*256 + lane*4, dst + j*256);
    }

    int cur = 0;
    for (int i = 0; i < TILES; ++i) {
        if (i + 1 < TILES) {
            const float* sp = src + (long long)(rowBlk + (i+1)*TROWS) * DD;
            float* dst = &buf[cur ^ 1][wv][0];
            #pragma unroll
            for (int j = 0; j < 4; ++j)
                GLD_LDS16(sp + j*256 + lane*4, dst + j*256);
            asm volatile("s_waitcnt vmcnt(4)" ::: "memory");  // tile i landed; i+1 in flight
        } else {
            asm volatile("s_waitcnt vmcnt(0)" ::: "memory");
        }
        __builtin_amdgcn_s_barrier();
        __builtin_amdgcn_sched_barrier(0);

        float4 rv = *(const float4*)(&buf[cur][0][hw*DD + d0]);
        float4 tv = *(const float4*)(&buf[cur][1][hw*DD + d0]);
        float4 mv = *(const float4*)(&buf[cur][2][hw*DD + d0]);
        float4 hv = *(const float4*)(&buf[cur][3][hw*DD + d0]);

        double z1 = dot4d(rv, w0) + dot4d(tv, w1) + dot4d(mv, w2);
        double z2 = dot4d(hv, wr);
        #pragma unroll
        for (int o = 16; o > 0; o >>= 1) {
            z1 += __shfl_xor(z1, o);
            z2 += __shfl_xor(z2, o);
        }
        double x   = (lane & 1) ? (z2 + br) : (z1 + cb);
        double ex  = exp(-x);
        double exo = __shfl_xor(ex, 1);
        double att = 0.5 * (2.0 + ex + exo) / ((1.0 + ex) * (1.0 + exo));

        if (sl == 0) {
            int row = rowBlk + i*TROWS + hw;
            attArr[row] = att;
            int t = tpre[i];
            unsafeAtomicAdd(&agg_att[t], att);
            int c = atomicAdd(&counts[t], 1);
            if (c < CAP) list2[t*CAP + c] = row;
            else { int p = atomicAdd(ovCnt, 1); if (p < OVCAP) ovBuf[p] = make_int2(t, row); }
        }
        __builtin_amdgcn_sched_barrier(0);
        __builtin_amdgcn_s_barrier();   // all done reading buf[cur] before overwrite
        cur ^= 1;
    }
}

// ---------------- exact top-k by rank selection ----------------
// rank(i) = #{j : v[j]>v[i] or (v[j]==v[i] and j<i)}; rank<K -> position rank.
// Identical semantics to sort-by-(value desc, index asc). 64 blocks x 512 thr.
__global__ __launch_bounds__(512) void k_rank(const double* __restrict__ agg_att,
                                              const int* __restrict__ tail_nodes,
                                              int* __restrict__ idx_out,
                                              float* __restrict__ out_nodes) {
    const int b = blockIdx.x >> 2;
    const int q = blockIdx.x & 3;
    __shared__ double v[MM];
    for (int i = threadIdx.x; i < MM; i += 512) v[i] = agg_att[b*MM + i];
    __syncthreads();
    const int i = q*512 + threadIdx.x;
    const double vi = v[i];
    int rank = 0;
    #pragma unroll 8
    for (int j = 0; j < MM; ++j) {
        double vj = v[j];
        rank += (vj > vi || (vj == vi && j < i)) ? 1 : 0;
    }
    if (rank < TOPKK) {
        int t = b*MM + i;
        idx_out[b*TOPKK + rank] = t;
        out_nodes[(b*TOPKK + rank)*2 + 0] = (float)tail_nodes[t*3 + 1];
        out_nodes[(b*TOPKK + rank)*2 + 1] = (float)tail_nodes[t*3 + 2];
    }
}

// ---------------- Fused Phase C + epilogue (winners only) ----------------
__global__ __launch_bounds__(256) void k_aggWO(const float* __restrict__ r_n,
                                               const float* __restrict__ tm_n,
                                               const float* __restrict__ hidden,
                                               const float* __restrict__ q_head,
                                               const float* __restrict__ tail_emd,
                                               const int* __restrict__ counts,
                                               const int* __restrict__ list2,
                                               const int* __restrict__ ovCnt,
                                               const int2* __restrict__ ovBuf,
                                               const double* __restrict__ attArr,
                                               const int* __restrict__ idx_ws,
                                               const float* __restrict__ Wout,
                                               const float* __restrict__ bout,
                                               float* __restrict__ out_emd,
                                               float* __restrict__ out_hid) {
    __shared__ float a_s[16][DD];   // 8KB
    const int tid = threadIdx.x;
    const int hw  = tid >> 5;
    const int sl  = tid & 31;
    const int d0  = 4 * sl;
    const int w0i = blockIdx.x * 16;

    #pragma unroll
    for (int rr = 0; rr < 2; ++rr) {
        const int wi = w0i + hw * 2 + rr;
        const int t  = idx_ws[wi];
        const int b  = t >> 11;
        const float4 qh = *(const float4*)(q_head + b*DD + d0);
        const int cnt = counts[t];
        const int n   = cnt < CAP ? cnt : CAP;

        float p0 = 0.f, p1 = 0.f, p2 = 0.f, p3 = 0.f;
        float h0 = 0.f, h1 = 0.f, h2 = 0.f, h3 = 0.f;
        double asum = 0.0;
        for (int e = 0; e < n; ++e) {
            int row = list2[t*CAP + e];
            long long base = (long long)row * DD + d0;
            float4 rv = *(const float4*)(r_n    + base);
            float4 mv = *(const float4*)(tm_n   + base);
            float4 hv = *(const float4*)(hidden + base);
            double attd = attArr[row];
            float  att  = (float)attd;
            p0 += att * (rv.x + mv.x); p1 += att * (rv.y + mv.y);
            p2 += att * (rv.z + mv.z); p3 += att * (rv.w + mv.w);
            h0 += hv.x; h1 += hv.y; h2 += hv.z; h3 += hv.w;
            asum += attd;
        }
        if (cnt > CAP) {  // essentially never; correctness fallback
            int m = *ovCnt; if (m > OVCAP) m = OVCAP;
            for (int k2 = 0; k2 < m; ++k2) {
                int2 pr = ovBuf[k2];
                if (pr.x == t) {
                    int row = pr.y;
                    long long base = (long long)row * DD + d0;
                    float4 rv = *(const float4*)(r_n    + base);
                    float4 mv = *(const float4*)(tm_n   + base);
                    float4 hv = *(const float4*)(hidden + base);
                    double attd = attArr[row];
                    float  att  = (float)attd;
                    p0 += att * (rv.x + mv.x); p1 += att * (rv.y + mv.y);
                    p2 += att * (rv.z + mv.z); p3 += att * (rv.w + mv.w);
                    h0 += hv.x; h1 += hv.y; h2 += hv.z; h3 += hv.w;
                    asum += attd;
                }
            }
        }
        float A = (float)asum;
        long long ot = (long long)t * DD + d0;
        float4 te = *(const float4*)(tail_emd + ot);
        float4 ta;
        ta.x = te.x + A*qh.x + p0; ta.y = te.y + A*qh.y + p1;
        ta.z = te.z + A*qh.z + p2; ta.w = te.w + A*qh.w + p3;
        *(float4*)(&a_s[hw*2 + rr][d0]) = ta;
        float4 nh; nh.x = h0; nh.y = h1; nh.z = h2; nh.w = h3;
        *(float4*)(out_hid + (long long)wi * DD + d0) = nh;
    }
    __syncthreads();

    // GEMM phase: 256 threads = 2 row-halves x 128 columns
    const int c  = tid & 127;
    const int j0 = (tid >> 7) * 8;
    float acc[8];
    const float bc = bout[c];
    #pragma unroll
    for (int j = 0; j < 8; ++j) acc[j] = bc;
    for (int d = 0; d < DD; ++d) {
        float wvv = Wout[d*DD + c];
        #pragma unroll
        for (int j = 0; j < 8; ++j)
            acc[j] = fmaf(a_s[j0 + j][d], wvv, acc[j]);
    }
    #pragma unroll
    for (int j = 0; j < 8; ++j)
        out_emd[(long long)(w0i + j0 + j) * DD + c] = acc[j];
}

extern "C" void kernel_launch(void* const* d_in, const int* in_sizes, int n_in,
                              void* d_out, int out_size, void* d_ws, size_t ws_size,
                              hipStream_t stream) {
    const float* q_head   = (const float*)d_in[0];
    const float* q_rel    = (const float*)d_in[1];
    const float* q_time   = (const float*)d_in[2];
    const float* r_n      = (const float*)d_in[3];
    const float* t_n      = (const float*)d_in[4];
    const float* tm_n     = (const float*)d_in[5];
    const float* hidden   = (const float*)d_in[6];
    const float* tail_emd = (const float*)d_in[7];
    const int*   tail_index = (const int*)d_in[8];
    const int*   tail_nodes = (const int*)d_in[9];
    const float* Wq   = (const float*)d_in[10];
    const float* bq   = (const float*)d_in[11];
    const float* Wa   = (const float*)d_in[12];
    const float* ba   = (const float*)d_in[13];
    const float* Watt = (const float*)d_in[14];
    const float* batt = (const float*)d_in[15];
    const float* Wrule = (const float*)d_in[16];
    const float* brule = (const float*)d_in[17];
    const float* Wout = (const float*)d_in[18];
    const float* bout = (const float*)d_in[19];

    char* ws = (char*)d_ws;
    int*    counts  = (int*)   (ws + WS_COUNTS);
    double* agg_att = (double*)(ws + WS_AGG);
    int*    ovCnt   = (int*)   (ws + WS_OVC);
    float*  w32     = (float*) (ws + WS_W32);
    double* c_all   = (double*)(ws + WS_C);
    int*    idx_ws  = (int*)   (ws + WS_IDX);
    double* attArr  = (double*)(ws + WS_ATT);
    int*    list2   = (int*)   (ws + WS_LIST2);
    int2*   ovBuf   = (int2*)  (ws + WS_OVBUF);

    float* out       = (float*)d_out;
    float* out_nodes = out;                      // B*TOPK*2
    float* out_emd   = out + BB*TOPKK*2;         // B*TOPK*D
    float* out_hid   = out_emd + BB*TOPKK*DD;    // B*TOPK*D

    // counts + agg_att + ovCnt adjacent: single memset
    hipMemsetAsync(counts, 0, 393280, stream);
    hipLaunchKernelGGL(k_prep, dim3(BB), dim3(DD), 0, stream,
                       q_head, q_rel, q_time, Wq, bq, Wa, ba, Watt, batt,
                       w32, c_all);
    hipLaunchKernelGGL(k_att, dim3(ATT_BLOCKS), dim3(256), 0, stream,
                       r_n, t_n, tm_n, hidden, w32, c_all, Wrule, brule,
                       tail_index, attArr, agg_att, counts, list2, ovCnt, ovBuf);
    hipLaunchKernelGGL(k_rank, dim3(BB*4), dim3(512), 0, stream,
                       agg_att, tail_nodes, idx_ws, out_nodes);
    hipLaunchKernelGGL(k_aggWO, dim3(WINS/16), dim3(256), 0, stream,
                       r_n, tm_n, hidden, q_head, tail_emd,
                       counts, list2, ovCnt, ovBuf, attArr, idx_ws,
                       Wout, bout, out_emd, out_hid);
}

// Round 11
// 126.402 us; speedup vs baseline: 1.4477x; 1.3788x over previous
//
#include <hip/hip_runtime.h>

// Problem constants (from reference setup_inputs)
#define BB    16
#define NN    8192
#define DD    128
#define MM    2048
#define TOPKK 512
#define TT    (BB*MM)     // 32768
#define BNN   (BB*NN)     // 131072
#define WINS  (BB*TOPKK)  // 8192
#define CAP   24          // max rows/segment slotted (Poisson(4): P(>=24) ~ 1e-12)
#define OVCAP 4096

// ---------------- workspace layout (bytes) ----------------
#define WS_COUNTS  0           // int[TT]        131072   } one memset
#define WS_AGG     131072      // double[TT]     262144   }
#define WS_OVC     393216      // int[16]        64       }
#define WS_W32     393280      // float[B*384]   24576
#define WS_C       417856      // double[B]      128
#define WS_IDX     417984      // int[WINS]      32768
#define WS_ATT     450752      // double[BNN]    1048576
#define WS_LIST2   1499328     // int[TT*CAP]    3145728
#define WS_OVBUF   4645056     // int2[OVCAP]    32768

// Per-batch precompute: query_b, alpha_b, w_b = Wa @ alpha_b (f32 out), c_b.
__global__ __launch_bounds__(128) void k_prep(const float* __restrict__ q_head,
                                              const float* __restrict__ q_rel,
                                              const float* __restrict__ q_time,
                                              const float* __restrict__ Wq,
                                              const float* __restrict__ bq,
                                              const float* __restrict__ Wa,
                                              const float* __restrict__ ba,
                                              const float* __restrict__ Watt,
                                              const float* __restrict__ batt,
                                              float* __restrict__ w32_out,  // B*384 f32
                                              double* __restrict__ c_out) { // B
    int b = blockIdx.x;
    int d = threadIdx.x; // 0..127
    __shared__ double x_s[3*DD];
    __shared__ double alpha_s[DD];
    __shared__ double kpart[DD];
    x_s[d]        = (double)q_head[b*DD + d];
    x_s[DD + d]   = (double)q_rel [b*DD + d];
    x_s[2*DD + d] = (double)q_time[b*DD + d];
    __syncthreads();

    double acc = (double)bq[d];
    for (int k = 0; k < 3*DD; ++k) acc += x_s[k] * (double)Wq[k*DD + d];

    double W1 = (double)Watt[d];
    double W2 = (double)Watt[DD + d];
    double W3 = (double)Watt[2*DD + d];
    double a  = W1 * acc - W2 + W3;
    alpha_s[d] = a;
    kpart[d]   = acc * (W2 + W3) + (double)ba[d] * a;
    __syncthreads();

    for (int kk = d; kk < 3*DD; kk += DD) {
        double s = 0.0;
        for (int dd = 0; dd < DD; ++dd) s += (double)Wa[kk*DD + dd] * alpha_s[dd];
        w32_out[b*3*DD + kk] = (float)s;   // per-batch f32 rounding (validated R4+)
    }
    if (d == 0) {
        double K = (double)batt[0];
        for (int dd = 0; dd < DD; ++dd) K += kpart[dd];
        c_out[b] = K;
    }
}

__device__ __forceinline__ double dot4d(const float4 a, const float4 w) {
    return (double)a.x*(double)w.x + (double)a.y*(double)w.y
         + (double)a.z*(double)w.z + (double)a.w*(double)w.w;
}

// ---------------- Phase A: one-shot streaming (R8 measured-best structure) ----
// One row per 32-lane half-wave, float4/lane. f64 dot/butterfly/exp for
// ranking accuracy; parity exp dedup; fused agg_att atomic + capped CSR fill.
__global__ __launch_bounds__(256) void k_att(const float* __restrict__ r_n,
                                             const float* __restrict__ t_n,
                                             const float* __restrict__ tm_n,
                                             const float* __restrict__ hidden,
                                             const float* __restrict__ w32_all,
                                             const double* __restrict__ c_all,
                                             const float* __restrict__ Wrule,
                                             const float* __restrict__ brule,
                                             const int* __restrict__ tail_index,
                                             double* __restrict__ attArr,
                                             double* __restrict__ agg_att,
                                             int* __restrict__ counts,
                                             int* __restrict__ list2,
                                             int* __restrict__ ovCnt,
                                             int2* __restrict__ ovBuf) {
    const int wave = threadIdx.x >> 6;
    const int lane = threadIdx.x & 63;
    const int half = lane >> 5;
    const int sl   = lane & 31;
    const int d0   = 4 * sl;
    const int row  = (blockIdx.x * 4 + wave) * 2 + half;
    const int b    = row >> 13;

    const float* w = w32_all + b * 3 * DD;
    const float4 w0 = *(const float4*)(w + d0);
    const float4 w1 = *(const float4*)(w + DD + d0);
    const float4 w2 = *(const float4*)(w + 2*DD + d0);
    const float4 wr = *(const float4*)(Wrule + d0);
    const double cb = c_all[b];
    const double br = (double)brule[0];

    long long base = (long long)row * DD + d0;
    float4 rv = *(const float4*)(r_n    + base);
    float4 tv = *(const float4*)(t_n    + base);
    float4 mv = *(const float4*)(tm_n   + base);
    float4 hv = *(const float4*)(hidden + base);

    double z1 = dot4d(rv, w0) + dot4d(tv, w1) + dot4d(mv, w2);
    double z2 = dot4d(hv, wr);
    #pragma unroll
    for (int o = 16; o > 0; o >>= 1) {
        z1 += __shfl_xor(z1, o);
        z2 += __shfl_xor(z2, o);
    }
    // parity exp dedup: even lanes exp(-(z1+cb)), odd lanes exp(-(z2+br))
    double x  = (lane & 1) ? (z2 + br) : (z1 + cb);
    double ex = exp(-x);
    double exo = __shfl_xor(ex, 1);
    double att = 0.5 * (2.0 + ex + exo) / ((1.0 + ex) * (1.0 + exo));

    if (sl == 0) {
        attArr[row] = att;
        int t = tail_index[row];
        unsafeAtomicAdd(&agg_att[t], att);
        int c = atomicAdd(&counts[t], 1);
        if (c < CAP) list2[t*CAP + c] = row;
        else { int p = atomicAdd(ovCnt, 1); if (p < OVCAP) ovBuf[p] = make_int2(t, row); }
    }
}

// ---------------- exact top-k by rank selection (4 threads per candidate) ----
// rank(i) = #{j : v[j]>v[i] or (v[j]==v[i] and j<i)}; rank<K -> position rank.
// Identical tie semantics to sort-by-(value desc, index asc).
// Grid: 16 batches x 16 i-chunks of 128; 512 thr = 128 i x 4 j-parts.
__global__ __launch_bounds__(512) void k_rank(const double* __restrict__ agg_att,
                                              const int* __restrict__ tail_nodes,
                                              int* __restrict__ idx_out,
                                              float* __restrict__ out_nodes) {
    const int b     = blockIdx.x >> 4;
    const int chunk = blockIdx.x & 15;
    __shared__ double v[MM];
    for (int i = threadIdx.x; i < MM; i += 512) v[i] = agg_att[b*MM + i];
    __syncthreads();
    const int iloc = threadIdx.x >> 2;        // 0..127
    const int part = threadIdx.x & 3;         // 0..3
    const int i    = chunk * 128 + iloc;
    const double vi = v[i];
    const int j0 = part * 512;
    int rank = 0;
    #pragma unroll 8
    for (int jj = 0; jj < 256; ++jj) {
        double2 p = *(const double2*)(&v[j0 + 2*jj]);
        int ja = j0 + 2*jj;
        rank += (p.x > vi || (p.x == vi && ja     < i)) ? 1 : 0;
        rank += (p.y > vi || (p.y == vi && ja + 1 < i)) ? 1 : 0;
    }
    rank += __shfl_xor(rank, 1);
    rank += __shfl_xor(rank, 2);
    if (part == 0 && rank < TOPKK) {
        int t = b*MM + i;
        idx_out[b*TOPKK + rank] = t;
        out_nodes[(b*TOPKK + rank)*2 + 0] = (float)tail_nodes[t*3 + 1];
        out_nodes[(b*TOPKK + rank)*2 + 1] = (float)tail_nodes[t*3 + 2];
    }
}

// ---------------- Fused Phase C + epilogue (winners only) ----------------
__global__ __launch_bounds__(256) void k_aggWO(const float* __restrict__ r_n,
                                               const float* __restrict__ tm_n,
                                               const float* __restrict__ hidden,
                                               const float* __restrict__ q_head,
                                               const float* __restrict__ tail_emd,
                                               const int* __restrict__ counts,
                                               const int* __restrict__ list2,
                                               const int* __restrict__ ovCnt,
                                               const int2* __restrict__ ovBuf,
                                               const double* __restrict__ attArr,
                                               const int* __restrict__ idx_ws,
                                               const float* __restrict__ Wout,
                                               const float* __restrict__ bout,
                                               float* __restrict__ out_emd,
                                               float* __restrict__ out_hid) {
    __shared__ float a_s[16][DD];   // 8KB
    const int tid = threadIdx.x;
    const int hw  = tid >> 5;
    const int sl  = tid & 31;
    const int d0  = 4 * sl;
    const int w0i = blockIdx.x * 16;

    #pragma unroll
    for (int rr = 0; rr < 2; ++rr) {
        const int wi = w0i + hw * 2 + rr;
        const int t  = idx_ws[wi];
        const int b  = t >> 11;
        const float4 qh = *(const float4*)(q_head + b*DD + d0);
        const int cnt = counts[t];
        const int n   = cnt < CAP ? cnt : CAP;

        float p0 = 0.f, p1 = 0.f, p2 = 0.f, p3 = 0.f;
        float h0 = 0.f, h1 = 0.f, h2 = 0.f, h3 = 0.f;
        double asum = 0.0;
        for (int e = 0; e < n; ++e) {
            int row = list2[t*CAP + e];
            long long base = (long long)row * DD + d0;
            float4 rv = *(const float4*)(r_n    + base);
            float4 mv = *(const float4*)(tm_n   + base);
            float4 hv = *(const float4*)(hidden + base);
            double attd = attArr[row];
            float  att  = (float)attd;
            p0 += att * (rv.x + mv.x); p1 += att * (rv.y + mv.y);
            p2 += att * (rv.z + mv.z); p3 += att * (rv.w + mv.w);
            h0 += hv.x; h1 += hv.y; h2 += hv.z; h3 += hv.w;
            asum += attd;
        }
        if (cnt > CAP) {  // essentially never; correctness fallback
            int m = *ovCnt; if (m > OVCAP) m = OVCAP;
            for (int k2 = 0; k2 < m; ++k2) {
                int2 pr = ovBuf[k2];
                if (pr.x == t) {
                    int row = pr.y;
                    long long base = (long long)row * DD + d0;
                    float4 rv = *(const float4*)(r_n    + base);
                    float4 mv = *(const float4*)(tm_n   + base);
                    float4 hv = *(const float4*)(hidden + base);
                    double attd = attArr[row];
                    float  att  = (float)attd;
                    p0 += att * (rv.x + mv.x); p1 += att * (rv.y + mv.y);
                    p2 += att * (rv.z + mv.z); p3 += att * (rv.w + mv.w);
                    h0 += hv.x; h1 += hv.y; h2 += hv.z; h3 += hv.w;
                    asum += attd;
                }
            }
        }
        float A = (float)asum;
        long long ot = (long long)t * DD + d0;
        float4 te = *(const float4*)(tail_emd + ot);
        float4 ta;
        ta.x = te.x + A*qh.x + p0; ta.y = te.y + A*qh.y + p1;
        ta.z = te.z + A*qh.z + p2; ta.w = te.w + A*qh.w + p3;
        *(float4*)(&a_s[hw*2 + rr][d0]) = ta;
        float4 nh; nh.x = h0; nh.y = h1; nh.z = h2; nh.w = h3;
        *(float4*)(out_hid + (long long)wi * DD + d0) = nh;
    }
    __syncthreads();

    // GEMM phase: 256 threads = 2 row-halves x 128 columns
    const int c  = tid & 127;
    const int j0 = (tid >> 7) * 8;
    float acc[8];
    const float bc = bout[c];
    #pragma unroll
    for (int j = 0; j < 8; ++j) acc[j] = bc;
    for (int d = 0; d < DD; ++d) {
        float wvv = Wout[d*DD + c];
        #pragma unroll
        for (int j = 0; j < 8; ++j)
            acc[j] = fmaf(a_s[j0 + j][d], wvv, acc[j]);
    }
    #pragma unroll
    for (int j = 0; j < 8; ++j)
        out_emd[(long long)(w0i + j0 + j) * DD + c] = acc[j];
}

extern "C" void kernel_launch(void* const* d_in, const int* in_sizes, int n_in,
                              void* d_out, int out_size, void* d_ws, size_t ws_size,
                              hipStream_t stream) {
    const float* q_head   = (const float*)d_in[0];
    const float* q_rel    = (const float*)d_in[1];
    const float* q_time   = (const float*)d_in[2];
    const float* r_n      = (const float*)d_in[3];
    const float* t_n      = (const float*)d_in[4];
    const float* tm_n     = (const float*)d_in[5];
    const float* hidden   = (const float*)d_in[6];
    const float* tail_emd = (const float*)d_in[7];
    const int*   tail_index = (const int*)d_in[8];
    const int*   tail_nodes = (const int*)d_in[9];
    const float* Wq   = (const float*)d_in[10];
    const float* bq   = (const float*)d_in[11];
    const float* Wa   = (const float*)d_in[12];
    const float* ba   = (const float*)d_in[13];
    const float* Watt = (const float*)d_in[14];
    const float* batt = (const float*)d_in[15];
    const float* Wrule = (const float*)d_in[16];
    const float* brule = (const float*)d_in[17];
    const float* Wout = (const float*)d_in[18];
    const float* bout = (const float*)d_in[19];

    char* ws = (char*)d_ws;
    int*    counts  = (int*)   (ws + WS_COUNTS);
    double* agg_att = (double*)(ws + WS_AGG);
    int*    ovCnt   = (int*)   (ws + WS_OVC);
    float*  w32     = (float*) (ws + WS_W32);
    double* c_all   = (double*)(ws + WS_C);
    int*    idx_ws  = (int*)   (ws + WS_IDX);
    double* attArr  = (double*)(ws + WS_ATT);
    int*    list2   = (int*)   (ws + WS_LIST2);
    int2*   ovBuf   = (int2*)  (ws + WS_OVBUF);

    float* out       = (float*)d_out;
    float* out_nodes = out;                      // B*TOPK*2
    float* out_emd   = out + BB*TOPKK*2;         // B*TOPK*D
    float* out_hid   = out_emd + BB*TOPKK*DD;    // B*TOPK*D

    // counts + agg_att + ovCnt adjacent: single memset
    hipMemsetAsync(counts, 0, 393280, stream);
    hipLaunchKernelGGL(k_prep, dim3(BB), dim3(DD), 0, stream,
                       q_head, q_rel, q_time, Wq, bq, Wa, ba, Watt, batt,
                       w32, c_all);
    hipLaunchKernelGGL(k_att, dim3(BNN/8), dim3(256), 0, stream,
                       r_n, t_n, tm_n, hidden, w32, c_all, Wrule, brule,
                       tail_index, attArr, agg_att, counts, list2, ovCnt, ovBuf);
    hipLaunchKernelGGL(k_rank, dim3(BB*16), dim3(512), 0, stream,
                       agg_att, tail_nodes, idx_ws, out_nodes);
    hipLaunchKernelGGL(k_aggWO, dim3(WINS/16), dim3(256), 0, stream,
                       r_n, tm_n, hidden, q_head, tail_emd,
                       counts, list2, ovCnt, ovBuf, attArr, idx_ws,
                       Wout, bout, out_emd, out_hid);
}

// Round 13
// 120.111 us; speedup vs baseline: 1.5235x; 1.0524x over previous
//
#include <hip/hip_runtime.h>

// Problem constants (from reference setup_inputs)
#define BB    16
#define NN    8192
#define DD    128
#define MM    2048
#define TOPKK 512
#define TT    (BB*MM)     // 32768
#define BNN   (BB*NN)     // 131072
#define WINS  (BB*TOPKK)  // 8192
#define CAP   24          // max rows/segment slotted (Poisson(4): P(>=24) ~ 1e-12)
#define OVCAP 4096

// ---------------- workspace layout (bytes) ----------------
#define WS_COUNTS  0           // int[TT]        131072   } one memset
#define WS_AGG     131072      // double[TT]     262144   }
#define WS_OVC     393216      // int[16]        64       }
#define WS_W32     393280      // float[B*384]   24576
#define WS_C       417856      // double[B]      128
#define WS_IDX     417984      // int[WINS]      32768
#define WS_ATT     450752      // double[BNN]    1048576
#define WS_LIST2   1499328     // int[TT*CAP]    3145728
#define WS_OVBUF   4645056     // int2[OVCAP]    32768

// Per-batch precompute: query_b, alpha_b, w_b = Wa @ alpha_b (f32 out), c_b.
__global__ __launch_bounds__(128) void k_prep(const float* __restrict__ q_head,
                                              const float* __restrict__ q_rel,
                                              const float* __restrict__ q_time,
                                              const float* __restrict__ Wq,
                                              const float* __restrict__ bq,
                                              const float* __restrict__ Wa,
                                              const float* __restrict__ ba,
                                              const float* __restrict__ Watt,
                                              const float* __restrict__ batt,
                                              float* __restrict__ w32_out,  // B*384 f32
                                              double* __restrict__ c_out) { // B
    int b = blockIdx.x;
    int d = threadIdx.x; // 0..127
    __shared__ double x_s[3*DD];
    __shared__ double alpha_s[DD];
    __shared__ double kpart[DD];
    x_s[d]        = (double)q_head[b*DD + d];
    x_s[DD + d]   = (double)q_rel [b*DD + d];
    x_s[2*DD + d] = (double)q_time[b*DD + d];
    __syncthreads();

    double acc = (double)bq[d];
    for (int k = 0; k < 3*DD; ++k) acc += x_s[k] * (double)Wq[k*DD + d];

    double W1 = (double)Watt[d];
    double W2 = (double)Watt[DD + d];
    double W3 = (double)Watt[2*DD + d];
    double a  = W1 * acc - W2 + W3;
    alpha_s[d] = a;
    kpart[d]   = acc * (W2 + W3) + (double)ba[d] * a;
    __syncthreads();

    for (int kk = d; kk < 3*DD; kk += DD) {
        double s = 0.0;
        for (int dd = 0; dd < DD; ++dd) s += (double)Wa[kk*DD + dd] * alpha_s[dd];
        w32_out[b*3*DD + kk] = (float)s;   // per-batch f32 rounding (validated R4+)
    }
    if (d == 0) {
        double K = (double)batt[0];
        for (int dd = 0; dd < DD; ++dd) K += kpart[dd];
        c_out[b] = K;
    }
}

__device__ __forceinline__ double dot4d(const float4 a, const float4 w) {
    return (double)a.x*(double)w.x + (double)a.y*(double)w.y
         + (double)a.z*(double)w.z + (double)a.w*(double)w.w;
}

// ---------------- Phase A: one-shot streaming (R8/R11 measured-best) ----
// One row per 32-lane half-wave, float4/lane. f64 dot/butterfly/exp for
// ranking accuracy; parity exp dedup; fused agg_att atomic + capped CSR fill.
__global__ __launch_bounds__(256) void k_att(const float* __restrict__ r_n,
                                             const float* __restrict__ t_n,
                                             const float* __restrict__ tm_n,
                                             const float* __restrict__ hidden,
                                             const float* __restrict__ w32_all,
                                             const double* __restrict__ c_all,
                                             const float* __restrict__ Wrule,
                                             const float* __restrict__ brule,
                                             const int* __restrict__ tail_index,
                                             double* __restrict__ attArr,
                                             double* __restrict__ agg_att,
                                             int* __restrict__ counts,
                                             int* __restrict__ list2,
                                             int* __restrict__ ovCnt,
                                             int2* __restrict__ ovBuf) {
    const int wave = threadIdx.x >> 6;
    const int lane = threadIdx.x & 63;
    const int half = lane >> 5;
    const int sl   = lane & 31;
    const int d0   = 4 * sl;
    const int row  = (blockIdx.x * 4 + wave) * 2 + half;
    const int b    = row >> 13;

    const float* w = w32_all + b * 3 * DD;
    const float4 w0 = *(const float4*)(w + d0);
    const float4 w1 = *(const float4*)(w + DD + d0);
    const float4 w2 = *(const float4*)(w + 2*DD + d0);
    const float4 wr = *(const float4*)(Wrule + d0);
    const double cb = c_all[b];
    const double br = (double)brule[0];

    long long base = (long long)row * DD + d0;
    float4 rv = *(const float4*)(r_n    + base);
    float4 tv = *(const float4*)(t_n    + base);
    float4 mv = *(const float4*)(tm_n   + base);
    float4 hv = *(const float4*)(hidden + base);

    double z1 = dot4d(rv, w0) + dot4d(tv, w1) + dot4d(mv, w2);
    double z2 = dot4d(hv, wr);
    #pragma unroll
    for (int o = 16; o > 0; o >>= 1) {
        z1 += __shfl_xor(z1, o);
        z2 += __shfl_xor(z2, o);
    }
    // parity exp dedup: even lanes exp(-(z1+cb)), odd lanes exp(-(z2+br))
    double x  = (lane & 1) ? (z2 + br) : (z1 + cb);
    double ex = exp(-x);
    double exo = __shfl_xor(ex, 1);
    double att = 0.5 * (2.0 + ex + exo) / ((1.0 + ex) * (1.0 + exo));

    if (sl == 0) {
        attArr[row] = att;
        int t = tail_index[row];
        unsafeAtomicAdd(&agg_att[t], att);
        int c = atomicAdd(&counts[t], 1);
        if (c < CAP) list2[t*CAP + c] = row;
        else { int p = atomicAdd(ovCnt, 1); if (p < OVCAP) ovBuf[p] = make_int2(t, row); }
    }
}

// ---------------- exact top-k by rank selection (4 threads per candidate) ----
// rank(i) = #{j : v[j]>v[i] or (v[j]==v[i] and j<i)}; rank<K -> position rank.
// Identical tie semantics to sort-by-(value desc, index asc).
__global__ __launch_bounds__(512) void k_rank(const double* __restrict__ agg_att,
                                              const int* __restrict__ tail_nodes,
                                              int* __restrict__ idx_out,
                                              float* __restrict__ out_nodes) {
    const int b     = blockIdx.x >> 4;
    const int chunk = blockIdx.x & 15;
    __shared__ double v[MM];
    for (int i = threadIdx.x; i < MM; i += 512) v[i] = agg_att[b*MM + i];
    __syncthreads();
    const int iloc = threadIdx.x >> 2;        // 0..127
    const int part = threadIdx.x & 3;         // 0..3
    const int i    = chunk * 128 + iloc;
    const double vi = v[i];
    const int j0 = part * 512;
    int rank = 0;
    #pragma unroll 8
    for (int jj = 0; jj < 256; ++jj) {
        double2 p = *(const double2*)(&v[j0 + 2*jj]);
        int ja = j0 + 2*jj;
        rank += (p.x > vi || (p.x == vi && ja     < i)) ? 1 : 0;
        rank += (p.y > vi || (p.y == vi && ja + 1 < i)) ? 1 : 0;
    }
    rank += __shfl_xor(rank, 1);
    rank += __shfl_xor(rank, 2);
    if (part == 0 && rank < TOPKK) {
        int t = b*MM + i;
        idx_out[b*TOPKK + rank] = t;
        out_nodes[(b*TOPKK + rank)*2 + 0] = (float)tail_nodes[t*3 + 1];
        out_nodes[(b*TOPKK + rank)*2 + 1] = (float)tail_nodes[t*3 + 2];
    }
}

// ---------------- Fused Phase C + epilogue (winners only) ----------------
// 512 threads = 16 half-waves; ONE winner per half-wave.
__global__ __launch_bounds__(512) void k_aggWO(const float* __restrict__ r_n,
                                               const float* __restrict__ tm_n,
                                               const float* __restrict__ hidden,
                                               const float* __restrict__ q_head,
                                               const float* __restrict__ tail_emd,
                                               const int* __restrict__ counts,
                                               const int* __restrict__ list2,
                                               const int* __restrict__ ovCnt,
                                               const int2* __restrict__ ovBuf,
                                               const double* __restrict__ attArr,
                                               const int* __restrict__ idx_ws,
                                               const float* __restrict__ Wout,
                                               const float* __restrict__ bout,
                                               float* __restrict__ out_emd,
                                               float* __restrict__ out_hid) {
    __shared__ float a_s[16][DD];   // 8KB
    const int tid = threadIdx.x;
    const int hw  = tid >> 5;       // 0..15
    const int sl  = tid & 31;
    const int d0  = 4 * sl;
    const int w0i = blockIdx.x * 16;

    {
        const int wi = w0i + hw;
        const int t  = idx_ws[wi];
        const int b  = t >> 11;
        const float4 qh = *(const float4*)(q_head + b*DD + d0);
        const int cnt = counts[t];
        const int n   = cnt < CAP ? cnt : CAP;

        float p0 = 0.f, p1 = 0.f, p2 = 0.f, p3 = 0.f;
        float h0 = 0.f, h1 = 0.f, h2 = 0.f, h3 = 0.f;
        double asum = 0.0;
        for (int e = 0; e < n; ++e) {
            int row = list2[t*CAP + e];
            long long base = (long long)row * DD + d0;
            float4 rv = *(const float4*)(r_n    + base);
            float4 mv = *(const float4*)(tm_n   + base);
            float4 hv = *(const float4*)(hidden + base);
            double attd = attArr[row];
            float  att  = (float)attd;
            p0 += att * (rv.x + mv.x); p1 += att * (rv.y + mv.y);
            p2 += att * (rv.z + mv.z); p3 += att * (rv.w + mv.w);
            h0 += hv.x; h1 += hv.y; h2 += hv.z; h3 += hv.w;
            asum += attd;
        }
        if (cnt > CAP) {  // essentially never; correctness fallback
            int m = *ovCnt; if (m > OVCAP) m = OVCAP;
            for (int k2 = 0; k2 < m; ++k2) {
                int2 pr = ovBuf[k2];
                if (pr.x == t) {
                    int row = pr.y;
                    long long base = (long long)row * DD + d0;
                    float4 rv = *(const float4*)(r_n    + base);
                    float4 mv = *(const float4*)(tm_n   + base);
                    float4 hv = *(const float4*)(hidden + base);
                    double attd = attArr[row];
                    float  att  = (float)attd;
                    p0 += att * (rv.x + mv.x); p1 += att * (rv.y + mv.y);
                    p2 += att * (rv.z + mv.z); p3 += att * (rv.w + mv.w);
                    h0 += hv.x; h1 += hv.y; h2 += hv.z; h3 += hv.w;
                    asum += attd;
                }
            }
        }
        float A = (float)asum;
        long long ot = (long long)t * DD + d0;
        float4 te = *(const float4*)(tail_emd + ot);
        float4 ta;
        ta.x = te.x + A*qh.x + p0; ta.y = te.y + A*qh.y + p1;
        ta.z = te.z + A*qh.z + p2; ta.w = te.w + A*qh.w + p3;
        *(float4*)(&a_s[hw][d0]) = ta;
        float4 nh; nh.x = h0; nh.y = h1; nh.z = h2; nh.w = h3;
        *(float4*)(out_hid + (long long)wi * DD + d0) = nh;
    }
    __syncthreads();

    // GEMM phase: 512 threads = 4 row-quads x 128 columns
    const int c  = tid & 127;
    const int j0 = (tid >> 7) * 4;
    float acc[4];
    const float bc = bout[c];
    #pragma unroll
    for (int j = 0; j < 4; ++j) acc[j] = bc;
    for (int d = 0; d < DD; ++d) {
        float wvv = Wout[d*DD + c];
        #pragma unroll
        for (int j = 0; j < 4; ++j)
            acc[j] = fmaf(a_s[j0 + j][d], wvv, acc[j]);
    }
    #pragma unroll
    for (int j = 0; j < 4; ++j)
        out_emd[(long long)(w0i + j0 + j) * DD + c] = acc[j];
}

extern "C" void kernel_launch(void* const* d_in, const int* in_sizes, int n_in,
                              void* d_out, int out_size, void* d_ws, size_t ws_size,
                              hipStream_t stream) {
    const float* q_head   = (const float*)d_in[0];
    const float* q_rel    = (const float*)d_in[1];
    const float* q_time   = (const float*)d_in[2];
    const float* r_n      = (const float*)d_in[3];
    const float* t_n      = (const float*)d_in[4];
    const float* tm_n     = (const float*)d_in[5];
    const float* hidden   = (const float*)d_in[6];
    const float* tail_emd = (const float*)d_in[7];
    const int*   tail_index = (const int*)d_in[8];
    const int*   tail_nodes = (const int*)d_in[9];
    const float* Wq   = (const float*)d_in[10];
    const float* bq   = (const float*)d_in[11];
    const float* Wa   = (const float*)d_in[12];
    const float* ba   = (const float*)d_in[13];
    const float* Watt = (const float*)d_in[14];
    const float* batt = (const float*)d_in[15];
    const float* Wrule = (const float*)d_in[16];
    const float* brule = (const float*)d_in[17];
    const float* Wout = (const float*)d_in[18];
    const float* bout = (const float*)d_in[19];

    char* ws = (char*)d_ws;
    int*    counts  = (int*)   (ws + WS_COUNTS);
    double* agg_att = (double*)(ws + WS_AGG);
    int*    ovCnt   = (int*)   (ws + WS_OVC);
    float*  w32     = (float*) (ws + WS_W32);
    double* c_all   = (double*)(ws + WS_C);
    int*    idx_ws  = (int*)   (ws + WS_IDX);
    double* attArr  = (double*)(ws + WS_ATT);
    int*    list2   = (int*)   (ws + WS_LIST2);
    int2*   ovBuf   = (int2*)  (ws + WS_OVBUF);

    float* out       = (float*)d_out;
    float* out_nodes = out;                      // B*TOPK*2
    float* out_emd   = out + BB*TOPKK*2;         // B*TOPK*D
    float* out_hid   = out_emd + BB*TOPKK*DD;    // B*TOPK*D

    // counts + agg_att + ovCnt adjacent: single memset
    hipMemsetAsync(counts, 0, 393280, stream);
    hipLaunchKernelGGL(k_prep, dim3(BB), dim3(DD), 0, stream,
                       q_head, q_rel, q_time, Wq, bq, Wa, ba, Watt, batt,
                       w32, c_all);
    hipLaunchKernelGGL(k_att, dim3(BNN/8), dim3(256), 0, stream,
                       r_n, t_n, tm_n, hidden, w32, c_all, Wrule, brule,
                       tail_index, attArr, agg_att, counts, list2, ovCnt, ovBuf);
    hipLaunchKernelGGL(k_rank, dim3(BB*16), dim3(512), 0, stream,
                       agg_att, tail_nodes, idx_ws, out_nodes);
    hipLaunchKernelGGL(k_aggWO, dim3(WINS/16), dim3(512), 0, stream,
                       r_n, tm_n, hidden, q_head, tail_emd,
                       counts, list2, ovCnt, ovBuf, attArr, idx_ws,
                       Wout, bout, out_emd, out_hid);
}